// Round 3
// baseline (1048.809 us; speedup 1.0000x reference)
//
#include <hip/hip_runtime.h>

#define NN 100000
#define NE 1600000
#define DN 16
#define DE 8
#define H  32
#define NL 7
#define SCAN_T 1024
#define CHUNK ((NN + SCAN_T - 1) / SCAN_T)   // 98

// ---------------- sort machinery (runs once per call) ----------------

__global__ __launch_bounds__(256) void zero_cnt_kernel(int* __restrict__ cnt) {
    int i = blockIdx.x * blockDim.x + threadIdx.x;
    if (i < NN) cnt[i] = 0;
}

__global__ __launch_bounds__(256) void hist_kernel(const int* __restrict__ dst,
                                                   int* __restrict__ cnt) {
    int e = blockIdx.x * blockDim.x + threadIdx.x;
    if (e < NE) atomicAdd(&cnt[dst[e]], 1);
}

// single-block exclusive scan of cnt[NN] -> rowstart[NN+1], cursor[NN]
__global__ __launch_bounds__(SCAN_T) void scan_kernel(const int* __restrict__ cnt,
                                                      int* __restrict__ rowstart,
                                                      int* __restrict__ cursor) {
    __shared__ int part[SCAN_T];
    int t = threadIdx.x;
    int lo = t * CHUNK;
    int hi = lo + CHUNK; if (hi > NN) hi = NN;
    if (lo > NN) lo = NN;
    int s = 0;
    for (int i = lo; i < hi; ++i) s += cnt[i];
    part[t] = s;
    __syncthreads();
    for (int off = 1; off < SCAN_T; off <<= 1) {
        int add = (t >= off) ? part[t - off] : 0;
        __syncthreads();
        part[t] += add;
        __syncthreads();
    }
    int run = part[t] - s;          // exclusive offset of this chunk
    for (int i = lo; i < hi; ++i) {
        rowstart[i] = run;
        cursor[i]   = run;
        run += cnt[i];
    }
    if (t == SCAN_T - 1) rowstart[NN] = part[SCAN_T - 1];
}

// PERM=1: permute edge_attr into dst-sorted order (eas). PERM=0: store perm index only.
template<int PERM>
__global__ __launch_bounds__(256) void scatter_kernel(
        const int* __restrict__ src, const int* __restrict__ dst,
        const float* __restrict__ ea,
        int* __restrict__ cursor,
        int* __restrict__ es, float* __restrict__ eas, int* __restrict__ eperm) {
    int e = blockIdx.x * blockDim.x + threadIdx.x;
    if (e >= NE) return;
    int pos = atomicAdd(&cursor[dst[e]], 1);
    es[pos] = src[e];
    if (PERM) {
        const float4* s4 = (const float4*)(ea + (long)e * DE);
        float4 a = s4[0], b = s4[1];
        float4* d4 = (float4*)(eas + (long)pos * DE);
        d4[0] = a; d4[1] = b;
    } else {
        eperm[pos] = e;
    }
}

// ---------------- node init: h = x@W_node + b ; hm = h@Wm0_top + bm0 ----------------
__global__ __launch_bounds__(256) void init_kernel(
        const float* __restrict__ x,
        const float* __restrict__ W_node, const float* __restrict__ b_node,
        const float* __restrict__ Wm0, const float* __restrict__ bm0,
        float* __restrict__ h, float* __restrict__ hm)
{
    int n = blockIdx.x * blockDim.x + threadIdx.x;
    if (n >= NN) return;

    float xin[DN];
    #pragma unroll
    for (int k = 0; k < DN/4; ++k) {
        float4 v = ((const float4*)(x + (long)n*DN))[k];
        xin[4*k+0]=v.x; xin[4*k+1]=v.y; xin[4*k+2]=v.z; xin[4*k+3]=v.w;
    }
    float hv[H];
    #pragma unroll
    for (int j = 0; j < H; ++j) hv[j] = b_node[j];
    #pragma unroll
    for (int k = 0; k < DN; ++k)
        #pragma unroll
        for (int j = 0; j < H; ++j)
            hv[j] = fmaf(xin[k], W_node[k*H+j], hv[j]);

    #pragma unroll
    for (int j = 0; j < H/4; ++j)
        ((float4*)(h + (long)n*H))[j] = make_float4(hv[4*j],hv[4*j+1],hv[4*j+2],hv[4*j+3]);

    float hmv[H];
    #pragma unroll
    for (int j = 0; j < H; ++j) hmv[j] = bm0[j];
    #pragma unroll
    for (int k = 0; k < H; ++k)
        #pragma unroll
        for (int j = 0; j < H; ++j)
            hmv[j] = fmaf(hv[k], Wm0[k*H+j], hmv[j]);

    #pragma unroll
    for (int j = 0; j < H/4; ++j)
        ((float4*)(hm + (long)n*H))[j] = make_float4(hmv[4*j],hmv[4*j+1],hmv[4*j+2],hmv[4*j+3]);
}

// ---------------- per-layer aggregation: CSR gather-max, no atomics ----------------
// 8 lanes per node; lane `sub` owns channels [sub*4, sub*4+4). Unrolled by 2 for ILP.
template<int PERM>
__global__ __launch_bounds__(256) void aggr_kernel(
        const int* __restrict__ rowstart, const int* __restrict__ es,
        const float* __restrict__ eas,      // PERM=1: [E][DE] sorted
        const float* __restrict__ ea,       // PERM=0: original
        const int* __restrict__ eperm,      // PERM=0: sorted->orig index
        const float* __restrict__ Wm_bot,   // [DE][H]
        const float* __restrict__ hm,
        float* __restrict__ aggr)
{
    int tid  = blockIdx.x * blockDim.x + threadIdx.x;
    int node = tid >> 3;
    int sub  = tid & 7;
    if (node >= NN) return;

    float w[DE][4];
    #pragma unroll
    for (int k = 0; k < DE; ++k)
        #pragma unroll
        for (int c = 0; c < 4; ++c)
            w[k][c] = Wm_bot[k*H + sub*4 + c];

    float acc[4];
    #pragma unroll
    for (int c = 0; c < 4; ++c) acc[c] = -__builtin_inff();

    int lo = rowstart[node], hi = rowstart[node+1];
    int i = lo;
    for (; i + 1 < hi; i += 2) {
        int s0 = es[i], s1 = es[i+1];
        const float4* p0;
        const float4* p1;
        if (PERM) {
            p0 = (const float4*)(eas + (long)i * DE);
            p1 = (const float4*)(eas + (long)(i+1) * DE);
        } else {
            p0 = (const float4*)(ea + (long)eperm[i] * DE);
            p1 = (const float4*)(ea + (long)eperm[i+1] * DE);
        }
        float4 hv0 = *(const float4*)(hm + (long)s0*H + sub*4);
        float4 hv1 = *(const float4*)(hm + (long)s1*H + sub*4);
        float4 a0 = p0[0], b0 = p0[1];
        float4 a1 = p1[0], b1 = p1[1];
        float m0[4] = {hv0.x, hv0.y, hv0.z, hv0.w};
        float m1[4] = {hv1.x, hv1.y, hv1.z, hv1.w};
        #pragma unroll
        for (int c = 0; c < 4; ++c) {
            m0[c] = fmaf(a0.x, w[0][c], m0[c]);
            m1[c] = fmaf(a1.x, w[0][c], m1[c]);
            m0[c] = fmaf(a0.y, w[1][c], m0[c]);
            m1[c] = fmaf(a1.y, w[1][c], m1[c]);
            m0[c] = fmaf(a0.z, w[2][c], m0[c]);
            m1[c] = fmaf(a1.z, w[2][c], m1[c]);
            m0[c] = fmaf(a0.w, w[3][c], m0[c]);
            m1[c] = fmaf(a1.w, w[3][c], m1[c]);
            m0[c] = fmaf(b0.x, w[4][c], m0[c]);
            m1[c] = fmaf(b1.x, w[4][c], m1[c]);
            m0[c] = fmaf(b0.y, w[5][c], m0[c]);
            m1[c] = fmaf(b1.y, w[5][c], m1[c]);
            m0[c] = fmaf(b0.z, w[6][c], m0[c]);
            m1[c] = fmaf(b1.z, w[6][c], m1[c]);
            m0[c] = fmaf(b0.w, w[7][c], m0[c]);
            m1[c] = fmaf(b1.w, w[7][c], m1[c]);
            acc[c] = fmaxf(acc[c], fmaxf(m0[c], m1[c]));
        }
    }
    if (i < hi) {
        int s0 = es[i];
        const float4* p0 = PERM ? (const float4*)(eas + (long)i * DE)
                                : (const float4*)(ea + (long)eperm[i] * DE);
        float4 hv0 = *(const float4*)(hm + (long)s0*H + sub*4);
        float4 a0 = p0[0], b0 = p0[1];
        float m0[4] = {hv0.x, hv0.y, hv0.z, hv0.w};
        #pragma unroll
        for (int c = 0; c < 4; ++c) {
            m0[c] = fmaf(a0.x, w[0][c], m0[c]);
            m0[c] = fmaf(a0.y, w[1][c], m0[c]);
            m0[c] = fmaf(a0.z, w[2][c], m0[c]);
            m0[c] = fmaf(a0.w, w[3][c], m0[c]);
            m0[c] = fmaf(b0.x, w[4][c], m0[c]);
            m0[c] = fmaf(b0.y, w[5][c], m0[c]);
            m0[c] = fmaf(b0.z, w[6][c], m0[c]);
            m0[c] = fmaf(b0.w, w[7][c], m0[c]);
            acc[c] = fmaxf(acc[c], m0[c]);
        }
    }
    if (lo == hi) {
        #pragma unroll
        for (int c = 0; c < 4; ++c) acc[c] = 0.f;
    }
    *(float4*)(aggr + (long)node*H + sub*4) = make_float4(acc[0], acc[1], acc[2], acc[3]);
}

// ---------------- node update: relu(aggr@Wu+bu) + residual ; next hm or post ----------------
__global__ __launch_bounds__(256) void update_kernel(
        const float* __restrict__ Wu, const float* __restrict__ bu,
        const float* __restrict__ Wm_next, const float* __restrict__ bm_next, // null if last
        const float* __restrict__ W_post, const float* __restrict__ b_post,   // used if last
        float* __restrict__ h, float* __restrict__ hm,
        const float* __restrict__ aggr, float* __restrict__ out, int last)
{
    int n = blockIdx.x * blockDim.x + threadIdx.x;
    if (n >= NN) return;

    float av[H];
    #pragma unroll
    for (int j = 0; j < H/4; ++j) {
        float4 v = ((const float4*)(aggr + (long)n*H))[j];
        av[4*j+0]=v.x; av[4*j+1]=v.y; av[4*j+2]=v.z; av[4*j+3]=v.w;
    }

    float uv[H];
    #pragma unroll
    for (int j = 0; j < H; ++j) uv[j] = bu[j];
    #pragma unroll
    for (int k = 0; k < H; ++k)
        #pragma unroll
        for (int j = 0; j < H; ++j)
            uv[j] = fmaf(av[k], Wu[k*H+j], uv[j]);

    float hv[H];
    #pragma unroll
    for (int j = 0; j < H/4; ++j) {
        float4 v = ((const float4*)(h + (long)n*H))[j];
        hv[4*j+0]=v.x; hv[4*j+1]=v.y; hv[4*j+2]=v.z; hv[4*j+3]=v.w;
    }
    #pragma unroll
    for (int j = 0; j < H; ++j) hv[j] += fmaxf(uv[j], 0.f);

    #pragma unroll
    for (int j = 0; j < H/4; ++j)
        ((float4*)(h + (long)n*H))[j] = make_float4(hv[4*j],hv[4*j+1],hv[4*j+2],hv[4*j+3]);

    if (!last) {
        float hmv[H];
        #pragma unroll
        for (int j = 0; j < H; ++j) hmv[j] = bm_next[j];
        #pragma unroll
        for (int k = 0; k < H; ++k)
            #pragma unroll
            for (int j = 0; j < H; ++j)
                hmv[j] = fmaf(hv[k], Wm_next[k*H+j], hmv[j]);
        #pragma unroll
        for (int j = 0; j < H/4; ++j)
            ((float4*)(hm + (long)n*H))[j] = make_float4(hmv[4*j],hmv[4*j+1],hmv[4*j+2],hmv[4*j+3]);
    } else {
        float acc = b_post[0];
        #pragma unroll
        for (int k = 0; k < H; ++k) acc = fmaf(hv[k], W_post[k], acc);
        out[n] = acc;
    }
}

extern "C" void kernel_launch(void* const* d_in, const int* in_sizes, int n_in,
                              void* d_out, int out_size, void* d_ws, size_t ws_size,
                              hipStream_t stream)
{
    const float* x         = (const float*)d_in[0];
    const float* edge_attr = (const float*)d_in[1];
    const int*   edge_index= (const int*)  d_in[2];
    const float* W_node    = (const float*)d_in[3];
    const float* b_node    = (const float*)d_in[4];
    const float* Wm        = (const float*)d_in[5];   // [L][H+DE][H]
    const float* bm        = (const float*)d_in[6];   // [L][H]
    const float* Wu        = (const float*)d_in[7];   // [L][H][H]
    const float* bu        = (const float*)d_in[8];   // [L][H]
    const float* W_post    = (const float*)d_in[9];   // [H][1]
    const float* b_post    = (const float*)d_in[10];  // [1]
    float* out = (float*)d_out;

    const int* src = edge_index;        // row 0 (x_j source)
    const int* dst = edge_index + NE;   // row 1 (aggregation target)

    // workspace layout (all 16B-aligned)
    char* ws = (char*)d_ws;
    size_t off = 0;
    float* h        = (float*)(ws + off); off += (size_t)NN*H*4;        // 12.8 MB
    float* hm       = (float*)(ws + off); off += (size_t)NN*H*4;        // 12.8 MB
    float* aggr     = (float*)(ws + off); off += (size_t)NN*H*4;        // 12.8 MB
    int*   cnt      = (int*)  (ws + off); off += (size_t)NN*4;          // 0.4 MB
    int*   rowstart = (int*)  (ws + off); off += (size_t)(NN+16)*4;     // 0.4 MB
    int*   cursor   = (int*)  (ws + off); off += (size_t)NN*4;          // 0.4 MB
    int*   es       = (int*)  (ws + off); off += (size_t)NE*4;          // 6.4 MB
    size_t base = off;
    // PERM=1 layout: eas [E][DE] f32 (51.2 MB). PERM=0 layout: eperm [E] int (6.4 MB)
    const int use_perm = (ws_size >= base + (size_t)NE*DE*4);
    float* eas   = (float*)(ws + base);
    int*   eperm = (int*)  (ws + base);

    const int nodeBlocks  = (NN + 255) / 256;
    const int edgeBlocks  = (NE + 255) / 256;
    const int aggrBlocks  = (NN*8 + 255) / 256;

    // ---- build CSR (dst-sorted edge permutation) ----
    zero_cnt_kernel<<<nodeBlocks, 256, 0, stream>>>(cnt);
    hist_kernel<<<edgeBlocks, 256, 0, stream>>>(dst, cnt);
    scan_kernel<<<1, SCAN_T, 0, stream>>>(cnt, rowstart, cursor);
    if (use_perm)
        scatter_kernel<1><<<edgeBlocks, 256, 0, stream>>>(src, dst, edge_attr, cursor, es, eas, eperm);
    else
        scatter_kernel<0><<<edgeBlocks, 256, 0, stream>>>(src, dst, edge_attr, cursor, es, eas, eperm);

    // ---- node init ----
    init_kernel<<<nodeBlocks, 256, 0, stream>>>(x, W_node, b_node, Wm, bm, h, hm);

    // ---- layers ----
    for (int l = 0; l < NL; ++l) {
        const float* Wm_l   = Wm + (size_t)l*(H+DE)*H;
        const float* Wm_bot = Wm_l + (size_t)H*H;        // rows 32..39 multiply edge_attr
        const float* Wu_l   = Wu + (size_t)l*H*H;
        const float* bu_l   = bu + (size_t)l*H;
        int last = (l == NL-1);
        const float* Wm_next = last ? nullptr : Wm + (size_t)(l+1)*(H+DE)*H;
        const float* bm_next = last ? nullptr : bm + (size_t)(l+1)*H;

        if (use_perm)
            aggr_kernel<1><<<aggrBlocks, 256, 0, stream>>>(rowstart, es, eas, edge_attr, eperm,
                                                           Wm_bot, hm, aggr);
        else
            aggr_kernel<0><<<aggrBlocks, 256, 0, stream>>>(rowstart, es, eas, edge_attr, eperm,
                                                           Wm_bot, hm, aggr);
        update_kernel<<<nodeBlocks, 256, 0, stream>>>(Wu_l, bu_l, Wm_next, bm_next,
                                                      W_post, b_post, h, hm, aggr, out, last);
    }
}

// Round 5
// 946.602 us; speedup vs baseline: 1.1080x; 1.1080x over previous
//
#include <hip/hip_runtime.h>

#define NN 100000
#define NE 1600000
#define DN 16
#define DE 8
#define H  32
#define NL 7

#define SCAN_BT   1024                           // threads per scan block
#define SCAN_NB   ((NN + SCAN_BT - 1) / SCAN_BT) // 98 blocks
#define BSUM_T    128                            // >= SCAN_NB, power of 2

// ---------------- sort machinery (runs once per call) ----------------

__global__ __launch_bounds__(256) void zero_cnt_kernel(int* __restrict__ cnt) {
    int i = blockIdx.x * blockDim.x + threadIdx.x;
    if (i < NN) cnt[i] = 0;
}

__global__ __launch_bounds__(256) void hist_kernel(const int* __restrict__ dst,
                                                   int* __restrict__ cnt) {
    int e = blockIdx.x * blockDim.x + threadIdx.x;
    if (e < NE) atomicAdd(&cnt[dst[e]], 1);
}

// scan phase 1: per-block partial sums of cnt
__global__ __launch_bounds__(SCAN_BT) void scan_partial_kernel(
        const int* __restrict__ cnt, int* __restrict__ bsum) {
    __shared__ int red[SCAN_BT];
    int t = threadIdx.x;
    int i = blockIdx.x * SCAN_BT + t;
    red[t] = (i < NN) ? cnt[i] : 0;
    __syncthreads();
    for (int off = SCAN_BT / 2; off > 0; off >>= 1) {
        if (t < off) red[t] += red[t + off];
        __syncthreads();
    }
    if (t == 0) bsum[blockIdx.x] = red[0];
}

// scan phase 2: single small block scans the 98 block sums (exclusive)
__global__ __launch_bounds__(BSUM_T) void scan_bsum_kernel(
        const int* __restrict__ bsum, int* __restrict__ boff,
        int* __restrict__ rowstart /* writes rowstart[NN]=total */) {
    __shared__ int part[BSUM_T];
    int t = threadIdx.x;
    int v = (t < SCAN_NB) ? bsum[t] : 0;
    part[t] = v;
    __syncthreads();
    for (int off = 1; off < BSUM_T; off <<= 1) {
        int add = (t >= off) ? part[t - off] : 0;
        __syncthreads();
        part[t] += add;
        __syncthreads();
    }
    if (t < SCAN_NB) boff[t] = part[t] - v;           // exclusive
    if (t == BSUM_T - 1) rowstart[NN] = part[t];      // total == NE
}

// scan phase 3: per-block exclusive scan + block offset -> rowstart, cursor
__global__ __launch_bounds__(SCAN_BT) void scan_final_kernel(
        const int* __restrict__ cnt, const int* __restrict__ boff,
        int* __restrict__ rowstart, int* __restrict__ cursor) {
    __shared__ int part[SCAN_BT];
    int t = threadIdx.x;
    int i = blockIdx.x * SCAN_BT + t;
    int v = (i < NN) ? cnt[i] : 0;
    part[t] = v;
    __syncthreads();
    for (int off = 1; off < SCAN_BT; off <<= 1) {
        int add = (t >= off) ? part[t - off] : 0;
        __syncthreads();
        part[t] += add;
        __syncthreads();
    }
    if (i < NN) {
        int r = boff[blockIdx.x] + part[t] - v;       // exclusive
        rowstart[i] = r;
        cursor[i]   = r;
    }
}

// PERM=1: permute edge_attr into dst-sorted order (eas). PERM=0: store perm index only.
template<int PERM>
__global__ __launch_bounds__(256) void scatter_kernel(
        const int* __restrict__ src, const int* __restrict__ dst,
        const float* __restrict__ ea,
        int* __restrict__ cursor,
        int* __restrict__ es, float* __restrict__ eas, int* __restrict__ eperm) {
    int e = blockIdx.x * blockDim.x + threadIdx.x;
    if (e >= NE) return;
    int pos = atomicAdd(&cursor[dst[e]], 1);
    es[pos] = src[e];
    if (PERM) {
        const float4* s4 = (const float4*)(ea + (long)e * DE);
        float4 a = s4[0], b = s4[1];
        float4* d4 = (float4*)(eas + (long)pos * DE);
        d4[0] = a; d4[1] = b;
    } else {
        eperm[pos] = e;
    }
}

// ---------------- node init: h = x@W_node + b ; hm = h@Wm0_top + bm0 ----------------
__global__ __launch_bounds__(256) void init_kernel(
        const float* __restrict__ x,
        const float* __restrict__ W_node, const float* __restrict__ b_node,
        const float* __restrict__ Wm0, const float* __restrict__ bm0,
        float* __restrict__ h, float* __restrict__ hm)
{
    int n = blockIdx.x * blockDim.x + threadIdx.x;
    if (n >= NN) return;

    float xin[DN];
    #pragma unroll
    for (int k = 0; k < DN/4; ++k) {
        float4 v = ((const float4*)(x + (long)n*DN))[k];
        xin[4*k+0]=v.x; xin[4*k+1]=v.y; xin[4*k+2]=v.z; xin[4*k+3]=v.w;
    }
    float hv[H];
    #pragma unroll
    for (int j = 0; j < H; ++j) hv[j] = b_node[j];
    #pragma unroll
    for (int k = 0; k < DN; ++k)
        #pragma unroll
        for (int j = 0; j < H; ++j)
            hv[j] = fmaf(xin[k], W_node[k*H+j], hv[j]);

    #pragma unroll
    for (int j = 0; j < H/4; ++j)
        ((float4*)(h + (long)n*H))[j] = make_float4(hv[4*j],hv[4*j+1],hv[4*j+2],hv[4*j+3]);

    float hmv[H];
    #pragma unroll
    for (int j = 0; j < H; ++j) hmv[j] = bm0[j];
    #pragma unroll
    for (int k = 0; k < H; ++k)
        #pragma unroll
        for (int j = 0; j < H; ++j)
            hmv[j] = fmaf(hv[k], Wm0[k*H+j], hmv[j]);

    #pragma unroll
    for (int j = 0; j < H/4; ++j)
        ((float4*)(hm + (long)n*H))[j] = make_float4(hmv[4*j],hmv[4*j+1],hmv[4*j+2],hmv[4*j+3]);
}

// ---------------- per-layer aggregation: CSR gather-max, no atomics ----------------
// 16 lanes per node; lane `sub` owns channels [sub*2, sub*2+2). Unrolled by 2 for ILP.
template<int PERM>
__global__ __launch_bounds__(256) void aggr_kernel(
        const int* __restrict__ rowstart, const int* __restrict__ es,
        const float* __restrict__ eas,      // PERM=1: [E][DE] sorted
        const float* __restrict__ ea,       // PERM=0: original
        const int* __restrict__ eperm,      // PERM=0: sorted->orig index
        const float* __restrict__ Wm_bot,   // [DE][H]
        const float* __restrict__ hm,
        float* __restrict__ aggr)
{
    int tid  = blockIdx.x * blockDim.x + threadIdx.x;
    int node = tid >> 4;
    int sub  = tid & 15;
    if (node >= NN) return;

    float w0[DE], w1[DE];
    #pragma unroll
    for (int k = 0; k < DE; ++k) {
        w0[k] = Wm_bot[k*H + sub*2 + 0];
        w1[k] = Wm_bot[k*H + sub*2 + 1];
    }

    float acc0 = -__builtin_inff(), acc1 = -__builtin_inff();

    int lo = rowstart[node], hi = rowstart[node+1];
    int i = lo;
    for (; i + 1 < hi; i += 2) {
        int s0 = es[i], s1 = es[i+1];
        const float4* p0;
        const float4* p1;
        if (PERM) {
            p0 = (const float4*)(eas + (long)i * DE);
            p1 = (const float4*)(eas + (long)(i+1) * DE);
        } else {
            p0 = (const float4*)(ea + (long)eperm[i] * DE);
            p1 = (const float4*)(ea + (long)eperm[i+1] * DE);
        }
        float2 hv0 = *(const float2*)(hm + (long)s0*H + sub*2);
        float2 hv1 = *(const float2*)(hm + (long)s1*H + sub*2);
        float4 a0 = p0[0], b0 = p0[1];
        float4 a1 = p1[0], b1 = p1[1];
        float m00 = hv0.x, m01 = hv0.y;
        float m10 = hv1.x, m11 = hv1.y;
        m00 = fmaf(a0.x, w0[0], m00);  m01 = fmaf(a0.x, w1[0], m01);
        m10 = fmaf(a1.x, w0[0], m10);  m11 = fmaf(a1.x, w1[0], m11);
        m00 = fmaf(a0.y, w0[1], m00);  m01 = fmaf(a0.y, w1[1], m01);
        m10 = fmaf(a1.y, w0[1], m10);  m11 = fmaf(a1.y, w1[1], m11);
        m00 = fmaf(a0.z, w0[2], m00);  m01 = fmaf(a0.z, w1[2], m01);
        m10 = fmaf(a1.z, w0[2], m10);  m11 = fmaf(a1.z, w1[2], m11);
        m00 = fmaf(a0.w, w0[3], m00);  m01 = fmaf(a0.w, w1[3], m01);
        m10 = fmaf(a1.w, w0[3], m10);  m11 = fmaf(a1.w, w1[3], m11);
        m00 = fmaf(b0.x, w0[4], m00);  m01 = fmaf(b0.x, w1[4], m01);
        m10 = fmaf(b1.x, w0[4], m10);  m11 = fmaf(b1.x, w1[4], m11);
        m00 = fmaf(b0.y, w0[5], m00);  m01 = fmaf(b0.y, w1[5], m01);
        m10 = fmaf(b1.y, w0[5], m10);  m11 = fmaf(b1.y, w1[5], m11);
        m00 = fmaf(b0.z, w0[6], m00);  m01 = fmaf(b0.z, w1[6], m01);
        m10 = fmaf(b1.z, w0[6], m10);  m11 = fmaf(b1.z, w1[6], m11);
        m00 = fmaf(b0.w, w0[7], m00);  m01 = fmaf(b0.w, w1[7], m01);
        m10 = fmaf(b1.w, w0[7], m10);  m11 = fmaf(b1.w, w1[7], m11);
        acc0 = fmaxf(acc0, fmaxf(m00, m10));
        acc1 = fmaxf(acc1, fmaxf(m01, m11));
    }
    if (i < hi) {
        int s0 = es[i];
        const float4* p0 = PERM ? (const float4*)(eas + (long)i * DE)
                                : (const float4*)(ea + (long)eperm[i] * DE);
        float2 hv0 = *(const float2*)(hm + (long)s0*H + sub*2);
        float4 a0 = p0[0], b0 = p0[1];
        float m00 = hv0.x, m01 = hv0.y;
        m00 = fmaf(a0.x, w0[0], m00);  m01 = fmaf(a0.x, w1[0], m01);
        m00 = fmaf(a0.y, w0[1], m00);  m01 = fmaf(a0.y, w1[1], m01);
        m00 = fmaf(a0.z, w0[2], m00);  m01 = fmaf(a0.z, w1[2], m01);
        m00 = fmaf(a0.w, w0[3], m00);  m01 = fmaf(a0.w, w1[3], m01);
        m00 = fmaf(b0.x, w0[4], m00);  m01 = fmaf(b0.x, w1[4], m01);
        m00 = fmaf(b0.y, w0[5], m00);  m01 = fmaf(b0.y, w1[5], m01);
        m00 = fmaf(b0.z, w0[6], m00);  m01 = fmaf(b0.z, w1[6], m01);
        m00 = fmaf(b0.w, w0[7], m00);  m01 = fmaf(b0.w, w1[7], m01);
        acc0 = fmaxf(acc0, m00);
        acc1 = fmaxf(acc1, m01);
    }
    if (lo == hi) { acc0 = 0.f; acc1 = 0.f; }
    *(float2*)(aggr + (long)node*H + sub*2) = make_float2(acc0, acc1);
}

// ---------------- node update: relu(aggr@Wu+bu) + residual ; next hm or post ----------------
__global__ __launch_bounds__(256) void update_kernel(
        const float* __restrict__ Wu, const float* __restrict__ bu,
        const float* __restrict__ Wm_next, const float* __restrict__ bm_next, // null if last
        const float* __restrict__ W_post, const float* __restrict__ b_post,   // used if last
        float* __restrict__ h, float* __restrict__ hm,
        const float* __restrict__ aggr, float* __restrict__ out, int last)
{
    int n = blockIdx.x * blockDim.x + threadIdx.x;
    if (n >= NN) return;

    float av[H];
    #pragma unroll
    for (int j = 0; j < H/4; ++j) {
        float4 v = ((const float4*)(aggr + (long)n*H))[j];
        av[4*j+0]=v.x; av[4*j+1]=v.y; av[4*j+2]=v.z; av[4*j+3]=v.w;
    }

    float uv[H];
    #pragma unroll
    for (int j = 0; j < H; ++j) uv[j] = bu[j];
    #pragma unroll
    for (int k = 0; k < H; ++k)
        #pragma unroll
        for (int j = 0; j < H; ++j)
            uv[j] = fmaf(av[k], Wu[k*H+j], uv[j]);

    float hv[H];
    #pragma unroll
    for (int j = 0; j < H/4; ++j) {
        float4 v = ((const float4*)(h + (long)n*H))[j];
        hv[4*j+0]=v.x; hv[4*j+1]=v.y; hv[4*j+2]=v.z; hv[4*j+3]=v.w;
    }
    #pragma unroll
    for (int j = 0; j < H; ++j) hv[j] += fmaxf(uv[j], 0.f);

    #pragma unroll
    for (int j = 0; j < H/4; ++j)
        ((float4*)(h + (long)n*H))[j] = make_float4(hv[4*j],hv[4*j+1],hv[4*j+2],hv[4*j+3]);

    if (!last) {
        float hmv[H];
        #pragma unroll
        for (int j = 0; j < H; ++j) hmv[j] = bm_next[j];
        #pragma unroll
        for (int k = 0; k < H; ++k)
            #pragma unroll
            for (int j = 0; j < H; ++j)
                hmv[j] = fmaf(hv[k], Wm_next[k*H+j], hmv[j]);
        #pragma unroll
        for (int j = 0; j < H/4; ++j)
            ((float4*)(hm + (long)n*H))[j] = make_float4(hmv[4*j],hmv[4*j+1],hmv[4*j+2],hmv[4*j+3]);
    } else {
        float acc = b_post[0];
        #pragma unroll
        for (int k = 0; k < H; ++k) acc = fmaf(hv[k], W_post[k], acc);
        out[n] = acc;
    }
}

extern "C" void kernel_launch(void* const* d_in, const int* in_sizes, int n_in,
                              void* d_out, int out_size, void* d_ws, size_t ws_size,
                              hipStream_t stream)
{
    const float* x         = (const float*)d_in[0];
    const float* edge_attr = (const float*)d_in[1];
    const int*   edge_index= (const int*)  d_in[2];
    const float* W_node    = (const float*)d_in[3];
    const float* b_node    = (const float*)d_in[4];
    const float* Wm        = (const float*)d_in[5];   // [L][H+DE][H]
    const float* bm        = (const float*)d_in[6];   // [L][H]
    const float* Wu        = (const float*)d_in[7];   // [L][H][H]
    const float* bu        = (const float*)d_in[8];   // [L][H]
    const float* W_post    = (const float*)d_in[9];   // [H][1]
    const float* b_post    = (const float*)d_in[10];  // [1]
    float* out = (float*)d_out;

    const int* src = edge_index;        // row 0 (x_j source)
    const int* dst = edge_index + NE;   // row 1 (aggregation target)

    // workspace layout (all 16B-aligned)
    char* ws = (char*)d_ws;
    size_t off = 0;
    float* h        = (float*)(ws + off); off += (size_t)NN*H*4;        // 12.8 MB
    float* hm       = (float*)(ws + off); off += (size_t)NN*H*4;        // 12.8 MB
    float* aggr     = (float*)(ws + off); off += (size_t)NN*H*4;        // 12.8 MB
    int*   cnt      = (int*)  (ws + off); off += (size_t)NN*4;          // 0.4 MB
    int*   rowstart = (int*)  (ws + off); off += (size_t)(NN+16)*4;     // 0.4 MB
    int*   cursor   = (int*)  (ws + off); off += (size_t)NN*4;          // 0.4 MB
    int*   bsum     = (int*)  (ws + off); off += (size_t)256*4;
    int*   boff     = (int*)  (ws + off); off += (size_t)256*4;
    int*   es       = (int*)  (ws + off); off += (size_t)NE*4;          // 6.4 MB
    size_t base = off;
    // PERM=1 layout: eas [E][DE] f32 (51.2 MB). PERM=0 layout: eperm [E] int (6.4 MB)
    const int use_perm = (ws_size >= base + (size_t)NE*DE*4);
    float* eas   = (float*)(ws + base);
    int*   eperm = (int*)  (ws + base);

    const int nodeBlocks  = (NN + 255) / 256;
    const int edgeBlocks  = (NE + 255) / 256;
    const int aggrBlocks  = (NN*16 + 255) / 256;

    // ---- build CSR (dst-sorted edge permutation) ----
    zero_cnt_kernel<<<nodeBlocks, 256, 0, stream>>>(cnt);
    hist_kernel<<<edgeBlocks, 256, 0, stream>>>(dst, cnt);
    scan_partial_kernel<<<SCAN_NB, SCAN_BT, 0, stream>>>(cnt, bsum);
    scan_bsum_kernel<<<1, BSUM_T, 0, stream>>>(bsum, boff, rowstart);
    scan_final_kernel<<<SCAN_NB, SCAN_BT, 0, stream>>>(cnt, boff, rowstart, cursor);
    if (use_perm)
        scatter_kernel<1><<<edgeBlocks, 256, 0, stream>>>(src, dst, edge_attr, cursor, es, eas, eperm);
    else
        scatter_kernel<0><<<edgeBlocks, 256, 0, stream>>>(src, dst, edge_attr, cursor, es, eas, eperm);

    // ---- node init ----
    init_kernel<<<nodeBlocks, 256, 0, stream>>>(x, W_node, b_node, Wm, bm, h, hm);

    // ---- layers ----
    for (int l = 0; l < NL; ++l) {
        const float* Wm_l   = Wm + (size_t)l*(H+DE)*H;
        const float* Wm_bot = Wm_l + (size_t)H*H;        // rows 32..39 multiply edge_attr
        const float* Wu_l   = Wu + (size_t)l*H*H;
        const float* bu_l   = bu + (size_t)l*H;
        int last = (l == NL-1);
        const float* Wm_next = last ? nullptr : Wm + (size_t)(l+1)*(H+DE)*H;
        const float* bm_next = last ? nullptr : bm + (size_t)(l+1)*H;

        if (use_perm)
            aggr_kernel<1><<<aggrBlocks, 256, 0, stream>>>(rowstart, es, eas, edge_attr, eperm,
                                                           Wm_bot, hm, aggr);
        else
            aggr_kernel<0><<<aggrBlocks, 256, 0, stream>>>(rowstart, es, eas, edge_attr, eperm,
                                                           Wm_bot, hm, aggr);
        update_kernel<<<nodeBlocks, 256, 0, stream>>>(Wu_l, bu_l, Wm_next, bm_next,
                                                      W_post, b_post, h, hm, aggr, out, last);
    }
}